// Round 4
// baseline (2297.832 us; speedup 1.0000x reference)
//
#include <hip/hip_runtime.h>

#define NELEM  200000
#define NREACT 100000
#define EDIM   200
#define RDIM   128
#define F0     328
#define F0PAD  352      // K padded to multiple of 32 for layer 0
#define NH     3
#define MT     64       // rows per block tile (200000/64 = 3125 blocks)
#define NT     256      // 4 waves
#define SA     360      // wide LDS row stride (elems), 720 B rows
#define SB     264      // narrow LDS row stride, 528 B rows

typedef _Float16 f16x8 __attribute__((ext_vector_type(8)));
typedef float    f32x4 __attribute__((ext_vector_type(4)));

// ---------------- fused weight convert + transpose prepass ----------------
// src fp32 [H][K][N] -> dst fp16 [H][N][Kpad], zero-padded for k >= K
struct WSeg { const float* src; _Float16* dst; int K, N, Kpad, nb; };
struct WTab { WSeg s[10]; };

__global__ void wconv_all(WTab t)
{
    int b = blockIdx.x;
    for (int i = 0; i < 10; ++i) {
        if (b < t.s[i].nb) {
            const WSeg g = t.s[i];
            int h = b / g.N, n = b - h * g.N;
            const float* sp = g.src + (size_t)h * g.K * g.N + n;
            _Float16* dp = g.dst + (size_t)b * g.Kpad;
            for (int k = threadIdx.x; k < g.Kpad; k += blockDim.x)
                dp[k] = (k < g.K) ? (_Float16)sp[(size_t)k * g.N] : (_Float16)0.f;
            return;
        }
        b -= t.s[i].nb;
    }
}

// ---------------- one MFMA layer, ping-pong LDS ----------------
// bufIn[MT][SIN] -> bufOut[MT][SOUT]; wave computes cols [n0, n0+TN*16).
// PROJ: residual = A @ wRes (second MFMA chain).
// !PROJ: identity residual read from bufIn in epilogue (input intact: ping-pong).
// Caller barriers between layers.
template<int TN, int KSTEPS, int KPAD, int SIN, int SOUT, bool PROJ>
__device__ __forceinline__ void layer(
    const _Float16* __restrict__ bufIn, _Float16* __restrict__ bufOut,
    const _Float16* __restrict__ wFc, const _Float16* __restrict__ wRes,
    const float* __restrict__ bias, int n0, int lane)
{
    const int r = lane & 15, q = lane >> 4;
    f32x4 acc[4][TN];
    f32x4 racc[4][TN];
#pragma unroll
    for (int mt = 0; mt < 4; ++mt)
#pragma unroll
        for (int nt = 0; nt < TN; ++nt) {
            acc[mt][nt] = (f32x4){0.f, 0.f, 0.f, 0.f};
            if constexpr (PROJ) racc[mt][nt] = (f32x4){0.f, 0.f, 0.f, 0.f};
        }

    const _Float16* aBase  = bufIn + r * SIN + q * 8;
    const _Float16* wBase  = wFc + ((size_t)n0 + r) * KPAD + q * 8;
    const _Float16* wrBase = PROJ ? (wRes + ((size_t)n0 + r) * KPAD + q * 8) : wBase;

#pragma unroll
    for (int kt = 0; kt < KSTEPS; ++kt) {
        f16x8 a[4];
#pragma unroll
        for (int mt = 0; mt < 4; ++mt)
            a[mt] = *(const f16x8*)(aBase + mt * 16 * SIN + kt * 32);
#pragma unroll
        for (int nt = 0; nt < TN; ++nt) {
            f16x8 b = *(const f16x8*)(wBase + (size_t)nt * 16 * KPAD + kt * 32);
#pragma unroll
            for (int mt = 0; mt < 4; ++mt)
                acc[mt][nt] = __builtin_amdgcn_mfma_f32_16x16x32_f16(a[mt], b, acc[mt][nt], 0, 0, 0);
            if constexpr (PROJ) {
                f16x8 br = *(const f16x8*)(wrBase + (size_t)nt * 16 * KPAD + kt * 32);
#pragma unroll
                for (int mt = 0; mt < 4; ++mt)
                    racc[mt][nt] = __builtin_amdgcn_mfma_f32_16x16x32_f16(a[mt], br, racc[mt][nt], 0, 0, 0);
            }
        }
    }

    // epilogue: C/D layout col = lane&15 (r), row = q*4 + i (+ mt*16)
#pragma unroll
    for (int nt = 0; nt < TN; ++nt) {
        float bval = bias[n0 + nt * 16 + r];
        const int col = n0 + nt * 16 + r;
#pragma unroll
        for (int mt = 0; mt < 4; ++mt) {
#pragma unroll
            for (int i = 0; i < 4; ++i) {
                const int m = mt * 16 + q * 4 + i;
                float z = fmaxf(acc[mt][nt][i] + bval, 0.f);
                if constexpr (PROJ) z += racc[mt][nt][i];
                else                z += (float)bufIn[m * SIN + col];
                bufOut[m * SOUT + col] = (_Float16)z;
            }
        }
    }
}

// ---------------- fused MLP kernel ----------------
__global__ __launch_bounds__(NT, 2)
void mlp_mfma(const float* __restrict__ elem, const int* __restrict__ ridx,
              const float* __restrict__ embed,
              const _Float16* __restrict__ wb,
              const float* __restrict__ fcb0, const float* __restrict__ fcb1,
              const float* __restrict__ fcb2, const float* __restrict__ fcb3,
              const float* __restrict__ fcb4, const float* __restrict__ fcb5,
              const float* __restrict__ fcb6,
              const float* __restrict__ outW, const float* __restrict__ outb,
              float* __restrict__ gate, unsigned int* __restrict__ segmax)
{
    __shared__ __align__(16) _Float16 sX[MT * SA];   // 46080 B
    __shared__ __align__(16) _Float16 sY[MT * SB];   // 33792 B
    __shared__ int sidx[MT];

    const int tid = threadIdx.x, lane = tid & 63, wave = tid >> 6;
    const int head = blockIdx.y;
    const int row0 = blockIdx.x * MT;

    if (tid < MT) sidx[tid] = ridx[row0 + tid];
    __syncthreads();

    // stage concat(elem, embed[idx]) -> fp16 in sX, zero-pad k in [328,352)
    for (int rr = wave; rr < MT; rr += 4) {
        const float* es = elem + (size_t)(row0 + rr) * EDIM;
        const float* ms = embed + (size_t)sidx[rr] * RDIM;
        for (int k = lane; k < F0PAD; k += 64) {
            float v = (k < EDIM) ? es[k] : (k < F0 ? ms[k - EDIM] : 0.f);
            sX[rr * SA + k] = (_Float16)v;
        }
    }
    __syncthreads();

    const size_t h = head;
    const int n64 = wave * 64, n32 = wave * 32, n16 = wave * 16;

    // weight blob offsets (fp16 elems)
    const _Float16* wt_fc0  = wb;
    const _Float16* wt_res0 = wb + 270336;
    const _Float16* wt_fc1  = wb + 540672;
    const _Float16* wt_fc2  = wb + 737280;
    const _Float16* wt_fc3  = wb + 933888;
    const _Float16* wt_fc4  = wb + 1130496;
    const _Float16* wt_res4 = wb + 1228800;
    const _Float16* wt_fc5  = wb + 1327104;
    const _Float16* wt_fc6  = wb + 1376256;
    const _Float16* wt_res6 = wb + 1400832;

    layer<4, 11, 352, SA, SB, true >(sX, sY, wt_fc0 + h * 90112, wt_res0 + h * 90112,
                                     fcb0 + h * 256, n64, lane);
    __syncthreads();
    layer<4, 8, 256, SB, SA, false>(sY, sX, wt_fc1 + h * 65536, nullptr,
                                    fcb1 + h * 256, n64, lane);
    __syncthreads();
    layer<4, 8, 256, SA, SB, false>(sX, sY, wt_fc2 + h * 65536, nullptr,
                                    fcb2 + h * 256, n64, lane);
    __syncthreads();
    layer<4, 8, 256, SB, SA, false>(sY, sX, wt_fc3 + h * 65536, nullptr,
                                    fcb3 + h * 256, n64, lane);
    __syncthreads();
    layer<2, 8, 256, SA, SB, true >(sX, sY, wt_fc4 + h * 32768, wt_res4 + h * 32768,
                                    fcb4 + h * 128, n32, lane);
    __syncthreads();
    layer<2, 4, 128, SB, SA, false>(sY, sX, wt_fc5 + h * 16384, nullptr,
                                    fcb5 + h * 128, n32, lane);
    __syncthreads();
    layer<1, 4, 128, SA, SB, true >(sX, sY, wt_fc6 + h * 8192, wt_res6 + h * 8192,
                                    fcb6 + h * 64, n16, lane);
    __syncthreads();

    // gate = h64 . outW + outb ; one thread per row
    if (tid < MT) {
        const _Float16* hv = sY + tid * SB;
        const float* wv = outW + h * 64;
        float g = outb[head];
#pragma unroll
        for (int f = 0; f < 64; ++f) g = fmaf((float)hv[f], wv[f], g);
        gate[head * NELEM + row0 + tid] = g;
        unsigned int bits = __float_as_uint(g);
        unsigned int enc  = (bits & 0x80000000u) ? ~bits : (bits | 0x80000000u);
        atomicMax(&segmax[head * NREACT + sidx[tid]], enc);
    }
}

// ---------------- softmax phases ----------------
__global__ void phase2_kernel(float* __restrict__ gate, const int* __restrict__ ridx,
                              const unsigned int* __restrict__ segmax,
                              float* __restrict__ segsum)
{
    int i = blockIdx.x * blockDim.x + threadIdx.x;
    if (i >= NH * NELEM) return;
    int h = i / NELEM;
    int n = i - h * NELEM;
    int j = ridx[n];
    unsigned int enc  = segmax[h * NREACT + j];
    unsigned int bits = (enc & 0x80000000u) ? (enc & 0x7FFFFFFFu) : ~enc;
    float m = __uint_as_float(bits);
    float e = __expf(gate[i] - m);
    gate[i] = e;
    atomicAdd(&segsum[h * NREACT + j], e);
}

__global__ void phase3_kernel(const float* __restrict__ gate, const int* __restrict__ ridx,
                              const float* __restrict__ segsum, float* __restrict__ out)
{
    int n = blockIdx.x * blockDim.x + threadIdx.x;
    if (n >= NELEM) return;
    int j = ridx[n];
    float s = 0.0f;
#pragma unroll
    for (int h = 0; h < NH; ++h)
        s += gate[h * NELEM + n] / (segsum[h * NREACT + j] + 1e-13f);
    out[n] = s * (1.0f / 3.0f);
}

// ---------------- launcher ----------------
extern "C" void kernel_launch(void* const* d_in, const int* in_sizes, int n_in,
                              void* d_out, int out_size, void* d_ws, size_t ws_size,
                              hipStream_t stream)
{
    const float* elem  = (const float*)d_in[0];
    const int*   ridx  = (const int*)  d_in[1];
    const float* embed = (const float*)d_in[2];
    const float* fcW0  = (const float*)d_in[3];
    const float* fcb0  = (const float*)d_in[4];
    const float* fcW1  = (const float*)d_in[5];
    const float* fcb1  = (const float*)d_in[6];
    const float* fcW2  = (const float*)d_in[7];
    const float* fcb2  = (const float*)d_in[8];
    const float* fcW3  = (const float*)d_in[9];
    const float* fcb3  = (const float*)d_in[10];
    const float* fcW4  = (const float*)d_in[11];
    const float* fcb4  = (const float*)d_in[12];
    const float* fcW5  = (const float*)d_in[13];
    const float* fcb5  = (const float*)d_in[14];
    const float* fcW6  = (const float*)d_in[15];
    const float* fcb6  = (const float*)d_in[16];
    const float* resW0 = (const float*)d_in[17];
    const float* resW4 = (const float*)d_in[18];
    const float* resW6 = (const float*)d_in[19];
    const float* outW  = (const float*)d_in[20];
    const float* outb  = (const float*)d_in[21];

    float*        gate   = (float*)d_ws;                  // 600000 f32
    unsigned int* segmax = (unsigned int*)d_ws + 600000;  // 300000 u32
    float*        segsum = (float*)d_ws + 900000;         // 300000 f32
    _Float16*     wbuf   = (_Float16*)((float*)d_ws + 1200000);

    hipMemsetAsync((void*)segmax, 0, sizeof(unsigned int) * 600000, stream);

    WTab t;
    t.s[0] = { fcW0,  wbuf,           328, 256, 352, 768 };
    t.s[1] = { resW0, wbuf + 270336,  328, 256, 352, 768 };
    t.s[2] = { fcW1,  wbuf + 540672,  256, 256, 256, 768 };
    t.s[3] = { fcW2,  wbuf + 737280,  256, 256, 256, 768 };
    t.s[4] = { fcW3,  wbuf + 933888,  256, 256, 256, 768 };
    t.s[5] = { fcW4,  wbuf + 1130496, 256, 128, 256, 384 };
    t.s[6] = { resW4, wbuf + 1228800, 256, 128, 256, 384 };
    t.s[7] = { fcW5,  wbuf + 1327104, 128, 128, 128, 384 };
    t.s[8] = { fcW6,  wbuf + 1376256, 128,  64, 128, 192 };
    t.s[9] = { resW6, wbuf + 1400832, 128,  64, 128, 192 };
    wconv_all<<<5376, 128, 0, stream>>>(t);

    dim3 grid(NELEM / MT, NH);
    mlp_mfma<<<grid, NT, 0, stream>>>(elem, ridx, embed, wbuf,
                                      fcb0, fcb1, fcb2, fcb3, fcb4, fcb5, fcb6,
                                      outW, outb, gate, segmax);

    int tot = NH * NELEM;
    phase2_kernel<<<(tot + 255) / 256, 256, 0, stream>>>(gate, ridx, segmax, segsum);
    phase3_kernel<<<(NELEM + 255) / 256, 256, 0, stream>>>(gate, ridx, segsum, (float*)d_out);
}

// Round 5
// 1941.977 us; speedup vs baseline: 1.1832x; 1.1832x over previous
//
#include <hip/hip_runtime.h>

#define NELEM  200000
#define NREACT 100000
#define EDIM   200
#define RDIM   128
#define F0     328
#define F0PAD  352      // K padded to multiple of 32 for layer 0
#define NH     3
#define MT     64       // rows per block tile (200000/64 = 3125 blocks)
#define NT     256      // 4 waves
#define SA     360      // LDS row stride (elems); 720 B rows; 8-row bank period (2-way, free)

typedef _Float16 f16x8 __attribute__((ext_vector_type(8)));
typedef float    f32x4 __attribute__((ext_vector_type(4)));

// ---------------- fused weight convert + transpose prepass ----------------
// src fp32 [H][K][N] -> dst fp16 [H][N][Kpad], zero-padded for k >= K
struct WSeg { const float* src; _Float16* dst; int K, N, Kpad, nb; };
struct WTab { WSeg s[10]; };

__global__ void wconv_all(WTab t)
{
    int b = blockIdx.x;
    for (int i = 0; i < 10; ++i) {
        if (b < t.s[i].nb) {
            const WSeg g = t.s[i];
            int h = b / g.N, n = b - h * g.N;
            const float* sp = g.src + (size_t)h * g.K * g.N + n;
            _Float16* dp = g.dst + (size_t)b * g.Kpad;
            for (int k = threadIdx.x; k < g.Kpad; k += blockDim.x)
                dp[k] = (k < g.K) ? (_Float16)sp[(size_t)k * g.N] : (_Float16)0.f;
            return;
        }
        b -= t.s[i].nb;
    }
}

// ---------------- identity-residual layer, in-place, manual pipeline ----------------
// buf[MT][SA] holds input (K wide), output (N wide) written in place.
// Wave computes cols [n0, n0+TN*16). Depth-1 prefetch of A/B fragments.
template<int TN, int KSTEPS, int KPAD>
__device__ __forceinline__ void layer_id(
    _Float16* __restrict__ buf,
    const _Float16* __restrict__ wFc,
    const float* __restrict__ bias, int n0, int lane)
{
    const int r = lane & 15, q = lane >> 4;
    f32x4 acc[4][TN];
#pragma unroll
    for (int mt = 0; mt < 4; ++mt)
#pragma unroll
        for (int nt = 0; nt < TN; ++nt) acc[mt][nt] = (f32x4){0.f, 0.f, 0.f, 0.f};

    const _Float16* aBase = buf + r * SA + q * 8;
    const _Float16* wBase = wFc + ((size_t)n0 + r) * KPAD + q * 8;

    f16x8 a[4], aN[4], b[TN], bN[TN];
#pragma unroll
    for (int mt = 0; mt < 4; ++mt) a[mt] = *(const f16x8*)(aBase + mt * 16 * SA);
#pragma unroll
    for (int nt = 0; nt < TN; ++nt) b[nt] = *(const f16x8*)(wBase + (size_t)nt * 16 * KPAD);

#pragma unroll
    for (int kt = 0; kt < KSTEPS; ++kt) {
        if (kt + 1 < KSTEPS) {
#pragma unroll
            for (int nt = 0; nt < TN; ++nt)
                bN[nt] = *(const f16x8*)(wBase + (size_t)nt * 16 * KPAD + (kt + 1) * 32);
#pragma unroll
            for (int mt = 0; mt < 4; ++mt)
                aN[mt] = *(const f16x8*)(aBase + mt * 16 * SA + (kt + 1) * 32);
        }
#pragma unroll
        for (int nt = 0; nt < TN; ++nt)
#pragma unroll
            for (int mt = 0; mt < 4; ++mt)
                acc[mt][nt] = __builtin_amdgcn_mfma_f32_16x16x32_f16(a[mt], b[nt], acc[mt][nt], 0, 0, 0);
#pragma unroll
        for (int nt = 0; nt < TN; ++nt) b[nt] = bN[nt];
#pragma unroll
        for (int mt = 0; mt < 4; ++mt) a[mt] = aN[mt];
    }

    __syncthreads();   // all waves' reads of buf complete before overwrite

#pragma unroll
    for (int nt = 0; nt < TN; ++nt) {
        const float bval = bias[n0 + nt * 16 + r];
        const int col = n0 + nt * 16 + r;
#pragma unroll
        for (int mt = 0; mt < 4; ++mt) {
#pragma unroll
            for (int i = 0; i < 4; ++i) {
                const int m = mt * 16 + q * 4 + i;
                float z = fmaxf(acc[mt][nt][i] + bval, 0.f) + (float)buf[m * SA + col];
                buf[m * SA + col] = (_Float16)z;   // same thread reads then writes
            }
        }
    }
    __syncthreads();   // outputs visible before next layer reads
}

// ---------------- projection-residual layer, in-place ----------------
template<int TN, int KSTEPS, int KPAD>
__device__ __forceinline__ void layer_proj(
    _Float16* __restrict__ buf,
    const _Float16* __restrict__ wFc, const _Float16* __restrict__ wRes,
    const float* __restrict__ bias, int n0, int lane)
{
    const int r = lane & 15, q = lane >> 4;
    f32x4 acc[4][TN], racc[4][TN];
#pragma unroll
    for (int mt = 0; mt < 4; ++mt)
#pragma unroll
        for (int nt = 0; nt < TN; ++nt) {
            acc[mt][nt]  = (f32x4){0.f, 0.f, 0.f, 0.f};
            racc[mt][nt] = (f32x4){0.f, 0.f, 0.f, 0.f};
        }

    const _Float16* aBase  = buf + r * SA + q * 8;
    const _Float16* wBase  = wFc + ((size_t)n0 + r) * KPAD + q * 8;
    const _Float16* wrBase = wRes + ((size_t)n0 + r) * KPAD + q * 8;

#pragma unroll
    for (int kt = 0; kt < KSTEPS; ++kt) {
        f16x8 a[4];
#pragma unroll
        for (int mt = 0; mt < 4; ++mt)
            a[mt] = *(const f16x8*)(aBase + mt * 16 * SA + kt * 32);
#pragma unroll
        for (int nt = 0; nt < TN; ++nt) {
            f16x8 b = *(const f16x8*)(wBase + (size_t)nt * 16 * KPAD + kt * 32);
#pragma unroll
            for (int mt = 0; mt < 4; ++mt)
                acc[mt][nt] = __builtin_amdgcn_mfma_f32_16x16x32_f16(a[mt], b, acc[mt][nt], 0, 0, 0);
            f16x8 br = *(const f16x8*)(wrBase + (size_t)nt * 16 * KPAD + kt * 32);
#pragma unroll
            for (int mt = 0; mt < 4; ++mt)
                racc[mt][nt] = __builtin_amdgcn_mfma_f32_16x16x32_f16(a[mt], br, racc[mt][nt], 0, 0, 0);
        }
    }

    __syncthreads();   // all waves' reads of buf complete before overwrite

#pragma unroll
    for (int nt = 0; nt < TN; ++nt) {
        const float bval = bias[n0 + nt * 16 + r];
        const int col = n0 + nt * 16 + r;
#pragma unroll
        for (int mt = 0; mt < 4; ++mt) {
#pragma unroll
            for (int i = 0; i < 4; ++i) {
                const int m = mt * 16 + q * 4 + i;
                float z = fmaxf(acc[mt][nt][i] + bval, 0.f) + racc[mt][nt][i];
                buf[m * SA + col] = (_Float16)z;
            }
        }
    }
    __syncthreads();
}

// ---------------- fused MLP kernel ----------------
__global__ __launch_bounds__(NT, 3)
void mlp_mfma(const float* __restrict__ elem, const int* __restrict__ ridx,
              const float* __restrict__ embed,
              const _Float16* __restrict__ wb,
              const float* __restrict__ fcb0, const float* __restrict__ fcb1,
              const float* __restrict__ fcb2, const float* __restrict__ fcb3,
              const float* __restrict__ fcb4, const float* __restrict__ fcb5,
              const float* __restrict__ fcb6,
              const float* __restrict__ outW, const float* __restrict__ outb,
              float* __restrict__ gate, unsigned int* __restrict__ segmax)
{
    __shared__ __align__(16) _Float16 sX[MT * SA];   // 46080 B, in-place all layers
    __shared__ int sidx[MT];

    const int tid = threadIdx.x, lane = tid & 63, wave = tid >> 6;
    const int head = blockIdx.y;
    const int row0 = blockIdx.x * MT;

    if (tid < MT) sidx[tid] = ridx[row0 + tid];
    __syncthreads();

    // stage concat(elem, embed[idx]) -> fp16 in sX, zero-pad k in [328,352)
    for (int rr = wave; rr < MT; rr += 4) {
        const float* es = elem + (size_t)(row0 + rr) * EDIM;
        const float* ms = embed + (size_t)sidx[rr] * RDIM;
        for (int k = lane; k < F0PAD; k += 64) {
            float v = (k < EDIM) ? es[k] : (k < F0 ? ms[k - EDIM] : 0.f);
            sX[rr * SA + k] = (_Float16)v;
        }
    }
    __syncthreads();

    const size_t h = head;
    const int n64 = wave * 64, n32 = wave * 32, n16 = wave * 16;

    // weight blob offsets (fp16 elems)
    const _Float16* wt_fc0  = wb;
    const _Float16* wt_res0 = wb + 270336;
    const _Float16* wt_fc1  = wb + 540672;
    const _Float16* wt_fc2  = wb + 737280;
    const _Float16* wt_fc3  = wb + 933888;
    const _Float16* wt_fc4  = wb + 1130496;
    const _Float16* wt_res4 = wb + 1228800;
    const _Float16* wt_fc5  = wb + 1327104;
    const _Float16* wt_fc6  = wb + 1376256;
    const _Float16* wt_res6 = wb + 1400832;

    layer_proj<4, 11, 352>(sX, wt_fc0 + h * 90112, wt_res0 + h * 90112, fcb0 + h * 256, n64, lane);
    layer_id  <4, 8, 256>(sX, wt_fc1 + h * 65536, fcb1 + h * 256, n64, lane);
    layer_id  <4, 8, 256>(sX, wt_fc2 + h * 65536, fcb2 + h * 256, n64, lane);
    layer_id  <4, 8, 256>(sX, wt_fc3 + h * 65536, fcb3 + h * 256, n64, lane);
    layer_proj<2, 8, 256>(sX, wt_fc4 + h * 32768, wt_res4 + h * 32768, fcb4 + h * 128, n32, lane);
    layer_id  <2, 4, 128>(sX, wt_fc5 + h * 16384, fcb5 + h * 128, n32, lane);
    layer_proj<1, 4, 128>(sX, wt_fc6 + h * 8192,  wt_res6 + h * 8192,  fcb6 + h * 64,  n16, lane);

    // gate = h64 . outW + outb ; one thread per row
    if (tid < MT) {
        const _Float16* hv = sX + tid * SA;
        const float* wv = outW + h * 64;
        float g = outb[head];
#pragma unroll
        for (int f = 0; f < 64; ++f) g = fmaf((float)hv[f], wv[f], g);
        gate[head * NELEM + row0 + tid] = g;
        unsigned int bits = __float_as_uint(g);
        unsigned int enc  = (bits & 0x80000000u) ? ~bits : (bits | 0x80000000u);
        atomicMax(&segmax[head * NREACT + sidx[tid]], enc);
    }
}

// ---------------- softmax phases ----------------
__global__ void phase2_kernel(float* __restrict__ gate, const int* __restrict__ ridx,
                              const unsigned int* __restrict__ segmax,
                              float* __restrict__ segsum)
{
    int i = blockIdx.x * blockDim.x + threadIdx.x;
    if (i >= NH * NELEM) return;
    int h = i / NELEM;
    int n = i - h * NELEM;
    int j = ridx[n];
    unsigned int enc  = segmax[h * NREACT + j];
    unsigned int bits = (enc & 0x80000000u) ? (enc & 0x7FFFFFFFu) : ~enc;
    float m = __uint_as_float(bits);
    float e = __expf(gate[i] - m);
    gate[i] = e;
    atomicAdd(&segsum[h * NREACT + j], e);
}

__global__ void phase3_kernel(const float* __restrict__ gate, const int* __restrict__ ridx,
                              const float* __restrict__ segsum, float* __restrict__ out)
{
    int n = blockIdx.x * blockDim.x + threadIdx.x;
    if (n >= NELEM) return;
    int j = ridx[n];
    float s = 0.0f;
#pragma unroll
    for (int h = 0; h < NH; ++h)
        s += gate[h * NELEM + n] / (segsum[h * NREACT + j] + 1e-13f);
    out[n] = s * (1.0f / 3.0f);
}

// ---------------- launcher ----------------
extern "C" void kernel_launch(void* const* d_in, const int* in_sizes, int n_in,
                              void* d_out, int out_size, void* d_ws, size_t ws_size,
                              hipStream_t stream)
{
    const float* elem  = (const float*)d_in[0];
    const int*   ridx  = (const int*)  d_in[1];
    const float* embed = (const float*)d_in[2];
    const float* fcW0  = (const float*)d_in[3];
    const float* fcb0  = (const float*)d_in[4];
    const float* fcW1  = (const float*)d_in[5];
    const float* fcb1  = (const float*)d_in[6];
    const float* fcW2  = (const float*)d_in[7];
    const float* fcb2  = (const float*)d_in[8];
    const float* fcW3  = (const float*)d_in[9];
    const float* fcb3  = (const float*)d_in[10];
    const float* fcW4  = (const float*)d_in[11];
    const float* fcb4  = (const float*)d_in[12];
    const float* fcW5  = (const float*)d_in[13];
    const float* fcb5  = (const float*)d_in[14];
    const float* fcW6  = (const float*)d_in[15];
    const float* fcb6  = (const float*)d_in[16];
    const float* resW0 = (const float*)d_in[17];
    const float* resW4 = (const float*)d_in[18];
    const float* resW6 = (const float*)d_in[19];
    const float* outW  = (const float*)d_in[20];
    const float* outb  = (const float*)d_in[21];

    float*        gate   = (float*)d_ws;                  // 600000 f32
    unsigned int* segmax = (unsigned int*)d_ws + 600000;  // 300000 u32
    float*        segsum = (float*)d_ws + 900000;         // 300000 f32
    _Float16*     wbuf   = (_Float16*)((float*)d_ws + 1200000);

    hipMemsetAsync((void*)segmax, 0, sizeof(unsigned int) * 600000, stream);

    WTab t;
    t.s[0] = { fcW0,  wbuf,           328, 256, 352, 768 };
    t.s[1] = { resW0, wbuf + 270336,  328, 256, 352, 768 };
    t.s[2] = { fcW1,  wbuf + 540672,  256, 256, 256, 768 };
    t.s[3] = { fcW2,  wbuf + 737280,  256, 256, 256, 768 };
    t.s[4] = { fcW3,  wbuf + 933888,  256, 256, 256, 768 };
    t.s[5] = { fcW4,  wbuf + 1130496, 256, 128, 256, 384 };
    t.s[6] = { resW4, wbuf + 1228800, 256, 128, 256, 384 };
    t.s[7] = { fcW5,  wbuf + 1327104, 128, 128, 128, 384 };
    t.s[8] = { fcW6,  wbuf + 1376256, 128,  64, 128, 192 };
    t.s[9] = { resW6, wbuf + 1400832, 128,  64, 128, 192 };
    wconv_all<<<5376, 128, 0, stream>>>(t);

    dim3 grid(NELEM / MT, NH);
    mlp_mfma<<<grid, NT, 0, stream>>>(elem, ridx, embed, wbuf,
                                      fcb0, fcb1, fcb2, fcb3, fcb4, fcb5, fcb6,
                                      outW, outb, gate, segmax);

    int tot = NH * NELEM;
    phase2_kernel<<<(tot + 255) / 256, 256, 0, stream>>>(gate, ridx, segmax, segsum);
    phase3_kernel<<<(NELEM + 255) / 256, 256, 0, stream>>>(gate, ridx, segsum, (float*)d_out);
}